// Round 10
// baseline (17.718 us; speedup 1.0000x reference)
//
#include <hip/hip_runtime.h>

#define NTIMES 8
#define NFREQS 64
#define NSRC   512
#define NBL    66
#define KHALF  33
#define C_MPS  299792458.0f

// DPP-based wave64 reduction (VALU-only, no LDS). Full sum lands in lane 63.
template <int CTRL, int ROW_MASK>
__device__ __forceinline__ float dpp_add(float v) {
    const int moved = __builtin_amdgcn_update_dpp(
        0, __builtin_bit_cast(int, v), CTRL, ROW_MASK, 0xf, true);
    return v + __builtin_bit_cast(float, moved);
}
__device__ __forceinline__ float wave_sum_lane63(float v) {
    v = dpp_add<0x111, 0xf>(v); // row_shr:1
    v = dpp_add<0x112, 0xf>(v); // row_shr:2
    v = dpp_add<0x114, 0xf>(v); // row_shr:4
    v = dpp_add<0x118, 0xf>(v); // row_shr:8  -> lane15 of each row = row sum
    v = dpp_add<0x142, 0xa>(v); // row_bcast:15 into rows 1,3
    v = dpp_add<0x143, 0xc>(v); // row_bcast:31 into rows 2,3 -> lane63 = total
    return v;
}

// Output: Re(vis): [2][2][66][8][64] float32 (135168 elems).
// Block = (t, f, khalf). Phase 1: 16 weight vectors + baseline metadata +
// class-sorted baseline order in LDS. Phase 2: each wave sweeps a CONTIGUOUS
// chunk of class-sorted baselines, register-caching the weight block and
// reloading it only on (wave-uniform) class change.
__global__ __launch_bounds__(512, 4) void rime_kernel(
    const float* __restrict__ sky,       // [2][2][64][512]
    const float* __restrict__ beam,      // [2][2][8][64][512]
    const float* __restrict__ antpos,    // [12][3]
    const float* __restrict__ svec,      // [8][3][512]
    const float* __restrict__ freqs,     // [64]
    const int*   __restrict__ ant2model, // [12]
    const int*   __restrict__ bls,       // [66][2]
    float*       __restrict__ out)
{
    __shared__ float  wsm[16 * NSRC]; // [c][pq][s], 32 KB
    __shared__ float4 btab[NBL];      // (blvec.xyz, bitcast class)
    __shared__ int    sorted[NBL];    // baseline ids ordered by (class, id)

    const int bid = blockIdx.x;
    const int f  = bid & (NFREQS - 1);
    const int t  = (bid >> 6) & (NTIMES - 1);
    const int kh = bid >> 9; // 0 or 1

    const int tid  = threadIdx.x; // 0..511
    const int lane = tid & 63;
    const int wv   = tid >> 6;    // 0..7

    // ---- Phase 1a: baseline metadata table (threads 0..65) ----
    if (tid < NBL) {
        const int a1 = bls[2 * tid + 0];
        const int a2 = bls[2 * tid + 1];
        float4 e;
        e.x = antpos[3 * a2 + 0] - antpos[3 * a1 + 0];
        e.y = antpos[3 * a2 + 1] - antpos[3 * a1 + 1];
        e.z = antpos[3 * a2 + 2] - antpos[3 * a1 + 2];
        e.w = __builtin_bit_cast(float, ant2model[a1] * 2 + ant2model[a2]);
        btab[tid] = e;
    }

    // ---- Phase 1b: thread == source; build 16 weight vectors in LDS ----
    {
        const int s = tid;
        const size_t beam_tf = (size_t)t * NFREQS * NSRC + (size_t)f * NSRC + s;
        float bv[2][2]; // [p][m]
        bv[0][0] = beam[(size_t)0 * NTIMES * NFREQS * NSRC + beam_tf];
        bv[0][1] = beam[(size_t)1 * NTIMES * NFREQS * NSRC + beam_tf];
        bv[1][0] = beam[(size_t)2 * NTIMES * NFREQS * NSRC + beam_tf];
        bv[1][1] = beam[(size_t)3 * NTIMES * NFREQS * NSRC + beam_tf];
        const size_t sky_f = (size_t)f * NSRC + s;
        float skv[4];
        skv[0] = sky[(size_t)0 * NFREQS * NSRC + sky_f];
        skv[1] = sky[(size_t)1 * NFREQS * NSRC + sky_f];
        skv[2] = sky[(size_t)2 * NFREQS * NSRC + sky_f];
        skv[3] = sky[(size_t)3 * NFREQS * NSRC + sky_f];
#pragma unroll
        for (int m1 = 0; m1 < 2; ++m1)
#pragma unroll
            for (int m2 = 0; m2 < 2; ++m2)
#pragma unroll
                for (int pq = 0; pq < 4; ++pq) {
                    const int p = pq >> 1, q = pq & 1;
                    wsm[((m1 * 2 + m2) * 4 + pq) * NSRC + s] =
                        bv[p][m1] * skv[pq] * bv[q][m2];
                }
    }

    __syncthreads(); // btab visible for ranking; wsm in flight

    // ---- Phase 1c: rank-sort baselines by (class, id) (threads 0..65) ----
    if (tid < NBL) {
        const int myc = __builtin_bit_cast(int, btab[tid].w);
        int rank = 0;
        for (int j = 0; j < NBL; ++j) {
            const int cj = __builtin_bit_cast(int, btab[j].w);
            rank += (cj < myc) || (cj == myc && j < tid);
        }
        sorted[rank] = tid;
    }

    // per-lane svec registers (baseline-invariant)
    const float4* sv4 = (const float4*)(svec + (size_t)t * 3 * NSRC);
    float4 vx[2], vy[2], vz[2];
#pragma unroll
    for (int it = 0; it < 2; ++it) {
        vx[it] = sv4[lane + 64 * it];
        vy[it] = sv4[128 + lane + 64 * it];
        vz[it] = sv4[256 + lane + 64 * it];
    }

    // phase in REVOLUTIONS for v_cos: rev = (-f/c) * (blvec . svec)
    const float coefrev = -freqs[f] / C_MPS;

    __syncthreads();

    // ---- Phase 2: wave wv owns a contiguous chunk of sorted positions ----
    const int cnt  = (wv == 0) ? 5 : 4;
    const int pos0 = kh * KHALF + ((wv == 0) ? 0 : (1 + 4 * wv));

    int ccur = -1;
    float4 w00[2], w01[2], w10[2], w11[2];

#pragma unroll
    for (int j = 0; j < 5; ++j) {
        if (j < cnt) {
            const int k = sorted[pos0 + j];
            const float4 m = btab[k];
            const int c = __builtin_bit_cast(int, m.w);
            if (c != ccur) { // wave-uniform: reload weight block from LDS
                ccur = c;
                const float4* wp = (const float4*)(wsm + (size_t)c * 4 * NSRC);
#pragma unroll
                for (int it = 0; it < 2; ++it) {
                    const int s4 = lane + 64 * it;
                    w00[it] = wp[s4];          // pq stride = 128 float4
                    w01[it] = wp[128 + s4];
                    w10[it] = wp[256 + s4];
                    w11[it] = wp[384 + s4];
                }
            }
            const float bxc = coefrev * m.x;
            const float byc = coefrev * m.y;
            const float bzc = coefrev * m.z;

            float a00 = 0.f, a01 = 0.f, a10 = 0.f, a11 = 0.f;
#pragma unroll
            for (int it = 0; it < 2; ++it) {
#define RIME_BODY(CX)                                                          \
                {                                                              \
                    const float rev = __builtin_amdgcn_fractf(                 \
                        bxc * vx[it].CX + byc * vy[it].CX + bzc * vz[it].CX);  \
                    const float cs = __builtin_amdgcn_cosf(rev);               \
                    a00 += w00[it].CX * cs;                                    \
                    a01 += w01[it].CX * cs;                                    \
                    a10 += w10[it].CX * cs;                                    \
                    a11 += w11[it].CX * cs;                                    \
                }
                RIME_BODY(x)
                RIME_BODY(y)
                RIME_BODY(z)
                RIME_BODY(w)
#undef RIME_BODY
            }

            const float s00 = wave_sum_lane63(a00);
            const float s01 = wave_sum_lane63(a01);
            const float s10 = wave_sum_lane63(a10);
            const float s11 = wave_sum_lane63(a11);

            if (lane == 63) {
                const int base = k * (NTIMES * NFREQS) + t * NFREQS + f;
                const int pqs  = NBL * NTIMES * NFREQS; // 33792
                out[base]           = s00;
                out[base + pqs]     = s01;
                out[base + 2 * pqs] = s10;
                out[base + 3 * pqs] = s11;
            }
        }
    }
}

extern "C" void kernel_launch(void* const* d_in, const int* in_sizes, int n_in,
                              void* d_out, int out_size, void* d_ws, size_t ws_size,
                              hipStream_t stream) {
    const float* sky     = (const float*)d_in[0];
    const float* beam    = (const float*)d_in[1];
    const float* antpos  = (const float*)d_in[2];
    const float* svec    = (const float*)d_in[3];
    const float* freqs   = (const float*)d_in[4];
    const int*   ant2mod = (const int*)d_in[5];
    const int*   bls     = (const int*)d_in[6];
    float*       out     = (float*)d_out;

    const int nblocks = NTIMES * NFREQS * 2; // 1024: (t, f, khalf)
    rime_kernel<<<nblocks, 512, 0, stream>>>(sky, beam, antpos, svec, freqs,
                                             ant2mod, bls, out);
}